// Round 13
// baseline (110.512 us; speedup 1.0000x reference)
//
#include <hip/hip_runtime.h>
#include <stdint.h>
#include <stddef.h>

// BalancedFocalLoss fused kernel — MI355X (gfx950), round 12 (resubmit; R12
// bench failed on GPU acquisition, kernel unmeasured)
//
//   z = concat(zx, zy); zn = z/||z||;  sim = zn·znT / 0.5
//   ce_i  = log( sum_{j != i} exp(sim_ij) ) - sim_{i,(i+B)%N}
//   out   = mean( ALPHA * (1-exp(-ce))^2 * ce )
//
// s2n = sqrt(2*log2e)*zn bf16 => acc = log2e*sim; exp(sim) == exp2(acc).
// R12: m201-style 256^2 tile, 8 waves (2M x 4N), per-wave 128x64 output,
// BK=64, double-buffered 128 KiB LDS, counted vmcnt(8) K-tile pipeline
// (R9's proven sync skeleton, 4x more MFMA per barrier). Upper triangle in
// 256^2 panels: 528 tiles; tile (P,Q) emits row-sums -> slot Q and col-sums
// -> slot P of partial[32][8192] (each slot written exactly once; no
// atomics). XCD x owns pair-columns {2x, 2x+1} (66 tiles exact). Diag tiles
// stage B redundantly (uniform 8 loads/wave/K-tile keeps vmcnt counts
// exact). All partial stores deferred to an end flush via LDS stash.

typedef __attribute__((ext_vector_type(8))) short short8;
typedef __attribute__((ext_vector_type(4))) float f32x4;

#define NROWS 8192
#define DDIM 256

__device__ __forceinline__ unsigned short f2bf(float f) {
  unsigned int u = __float_as_uint(f);
  u = (u + 0x7FFFu + ((u >> 16) & 1u)) >> 16;   // RNE, inputs finite
  return (unsigned short)u;
}

// ---------------- 1. normalize + sqrt(2*log2e) scale + bf16; zero d1 counter ----------------
__global__ __launch_bounds__(256) void norm_kernel(const float* __restrict__ zx,
                                                   const float* __restrict__ zy,
                                                   unsigned short* __restrict__ zn,
                                                   unsigned int* __restrict__ counter) {
  if (blockIdx.x == 0 && threadIdx.x == 0) *counter = 0u;
  const int row = blockIdx.x * 4 + (threadIdx.x >> 6);   // 8192 rows, 1 per wave
  const int lane = threadIdx.x & 63;
  const float* src = (row < 4096) ? (zx + (size_t)row * DDIM)
                                  : (zy + (size_t)(row - 4096) * DDIM);
  float4 v = reinterpret_cast<const float4*>(src)[lane];
  float ss = v.x * v.x + v.y * v.y + v.z * v.z + v.w * v.w;
#pragma unroll
  for (int m = 1; m < 64; m <<= 1) ss += __shfl_xor(ss, m);
  const float sc = 1.69864360f * rsqrtf(ss);   // sqrt(2*log2e)/||z||
  ushort4 o;
  o.x = f2bf(v.x * sc); o.y = f2bf(v.y * sc);
  o.z = f2bf(v.z * sc); o.w = f2bf(v.w * sc);
  reinterpret_cast<ushort4*>(zn + (size_t)row * DDIM)[lane] = o;
}

// ---------------- 2. upper-triangle 256^2 sim GEMM + exp2 row/col sums ----------------
__global__ __launch_bounds__(512, 2) void simtri_kernel(const unsigned short* __restrict__ zn,
                                                        float* __restrict__ partial,
                                                        float* __restrict__ pos) {
  __shared__ unsigned short smem[2][4][128 * 64];   // 128 KiB: [buf][Ah0,Ah1,Bh0,Bh1]
  __shared__ float tmp_r[4][256];                   // cross-wave row reduce (wn)
  __shared__ float tmp_c[2][256];                   // cross-wave col reduce (wm)
  __shared__ float stashf[3][2][256];               // deferred partials per tile

  // XCD x owns pair-columns {2x, 2x+1}: pair pc has 33 tiles (q=pc: p=0..pc;
  // q=31-pc: p=0..31-pc). 66 tiles over 32 blocks: block l gets local ranks
  // {l, l+32} and l<2 also {64+l}.
  const int x = blockIdx.x & 7;
  const int l = blockIdx.x >> 3;          // 0..31
  const int nt = (l < 2) ? 3 : 2;
  int TP[3], TQ[3];
  for (int i = 0; i < 3; ++i) {
    const int r = (i == 2) ? (64 + l) : (l + 32 * i);
    int pc, rr;
    if (r < 33) { pc = 2 * x;     rr = r; }
    else        { pc = 2 * x + 1; rr = r - 33; }
    if (rr <= pc) { TP[i] = rr;          TQ[i] = pc; }
    else          { TP[i] = rr - pc - 1; TQ[i] = 31 - pc; }
  }

  const int tid = threadIdx.x;
  const int lane = tid & 63;
  const int wid = tid >> 6;         // 0..7
  const int wm = wid >> 2;          // 0/1  (M half)
  const int wn = wid & 3;           // 0..3 (N quarter)
  const int hi = lane >> 4, lo = lane & 15;
  const int sw = lo & 7;            // frag-read XOR (== row&7 of lane's rows)

  const f32x4 z4 = {0.f, 0.f, 0.f, 0.f};
  f32x4 acc[8][4];
#pragma unroll
  for (int m = 0; m < 8; ++m)
#pragma unroll
    for (int n = 0; n < 4; ++n) acc[m][n] = z4;

  // Stage one 128x64 half (16 KiB = 1024 units of 16B; 512 thr x 2 loads).
  // LDS dest LINEAR (global_load_lds requirement); global source pre-swizzled
  // so LDS[r][ul] holds global unit (ul ^ (r&7)); reads apply the same XOR.
  auto stage_half = [&](int b, int slot, int row0, int k0) {
    unsigned short* lb = &smem[b][slot][0];
#pragma unroll
    for (int j = 0; j < 2; ++j) {
      const int u = j * 512 + tid;                 // 0..1023
      const int r = u >> 3, ul = u & 7;
      const unsigned short* g =
          zn + (size_t)(row0 + r) * DDIM + k0 + ((ul ^ (r & 7)) << 3);
      unsigned short* ldst = lb + (size_t)(j * 512 + wid * 64) * 8;  // wave-uniform
      __builtin_amdgcn_global_load_lds(
          (const __attribute__((address_space(1))) void*)g,
          (__attribute__((address_space(3))) void*)ldst, 16, 0, 0);
    }
  };
  // One K-tile (BK=64) of tile (P,Q): A 256 rows + B 256 rows = 4 halves,
  // 8 global_load_lds per wave — ALWAYS all 4 (diag stages B redundantly).
  auto stage_kt = [&](int b, int P, int Q, int k0) {
    stage_half(b, 0, P * 256, k0);
    stage_half(b, 1, P * 256 + 128, k0);
    stage_half(b, 2, Q * 256, k0);
    stage_half(b, 3, Q * 256 + 128, k0);
  };

  // Consume one K-tile: 24 ds_read_b128 + 64 MFMA per wave, phase-split so
  // B-frags are reused across both 4-m MFMA clusters (setprio-wrapped).
  auto consume = [&](int b) {
    const unsigned short* A0 = &smem[b][wm][0];              // wave's 128 rows
    const unsigned short* B0 = &smem[b][2 + (wn >> 1)][0];
    const int brbase = (wn & 1) * 64;
#pragma unroll
    for (int ks = 0; ks < 2; ++ks) {
      const int ko = (((ks << 2) + hi) ^ sw) << 3;
      short8 af[4], bf4[4];
#pragma unroll
      for (int n = 0; n < 4; ++n)
        bf4[n] = *reinterpret_cast<const short8*>(B0 + (brbase + n * 16 + lo) * 64 + ko);
#pragma unroll
      for (int m = 0; m < 4; ++m)
        af[m] = *reinterpret_cast<const short8*>(A0 + (m * 16 + lo) * 64 + ko);
      __builtin_amdgcn_s_setprio(1);
#pragma unroll
      for (int m = 0; m < 4; ++m)
#pragma unroll
        for (int n = 0; n < 4; ++n)
          acc[m][n] = __builtin_amdgcn_mfma_f32_16x16x32_bf16(af[m], bf4[n], acc[m][n], 0, 0, 0);
      __builtin_amdgcn_s_setprio(0);
#pragma unroll
      for (int m = 0; m < 4; ++m)
        af[m] = *reinterpret_cast<const short8*>(A0 + ((m + 4) * 16 + lo) * 64 + ko);
      __builtin_amdgcn_s_setprio(1);
#pragma unroll
      for (int m = 0; m < 4; ++m)
#pragma unroll
        for (int n = 0; n < 4; ++n)
          acc[m + 4][n] = __builtin_amdgcn_mfma_f32_16x16x32_bf16(af[m], bf4[n], acc[m + 4][n], 0, 0, 0);
      __builtin_amdgcn_s_setprio(0);
    }
  };

  // Epilogue: exp2, diag-exclude/pos harvest, cross-wave reduce, LDS stash.
  auto epilogue = [&](int si, int tp, int tq) {
    const bool isdiag = (tp == tq);
    const bool ispos = (tq == tp + 16);
    float rowp[8][4];
    float colp[4] = {0.f, 0.f, 0.f, 0.f};
#pragma unroll
    for (int m = 0; m < 8; ++m)
#pragma unroll
      for (int v = 0; v < 4; ++v) rowp[m][v] = 0.f;
#pragma unroll
    for (int m = 0; m < 8; ++m)
#pragma unroll
      for (int n = 0; n < 4; ++n)
#pragma unroll
        for (int v = 0; v < 4; ++v) {
          const float e = __builtin_amdgcn_exp2f(acc[m][n][v]);
          rowp[m][v] += e;
          colp[n] += e;
        }
    if (isdiag || ispos) {
#pragma unroll
      for (int m = 0; m < 8; ++m)
#pragma unroll
        for (int n = 0; n < 4; ++n)
#pragma unroll
          for (int v = 0; v < 4; ++v) {
            const int lr = wm * 128 + m * 16 + (hi << 2) + v;
            const int lc = wn * 64 + n * 16 + lo;
            if (lr == lc) {
              if (isdiag) rowp[m][v] -= __builtin_amdgcn_exp2f(acc[m][n][v]);
              else        pos[tp * 256 + lr] = acc[m][n][v];   // log2-domain
            }
          }
    }
    // row partials: reduce across 16 lo-lanes -> tmp_r[wn][.]
#pragma unroll
    for (int m = 0; m < 8; ++m)
#pragma unroll
      for (int v = 0; v < 4; ++v) {
        float s = rowp[m][v];
        s += __shfl_xor(s, 1); s += __shfl_xor(s, 2);
        s += __shfl_xor(s, 4); s += __shfl_xor(s, 8);
        if (lo == 0) tmp_r[wn][wm * 128 + m * 16 + (hi << 2) + v] = s;
      }
    // col partials: reduce across 4 hi-groups -> tmp_c[wm][.]
#pragma unroll
    for (int n = 0; n < 4; ++n) {
      float s = colp[n];
      s += __shfl_xor(s, 16); s += __shfl_xor(s, 32);
      if (lane < 16) tmp_c[wm][wn * 64 + n * 16 + lo] = s;
    }
    __syncthreads();
    if (tid < 256) {
      stashf[si][0][tid] = tmp_r[0][tid] + tmp_r[1][tid] + tmp_r[2][tid] + tmp_r[3][tid];
    } else {
      const int cc = tid - 256;
      stashf[si][1][cc] = tmp_c[0][cc] + tmp_c[1][cc];
    }
  };

  // ---- pipeline: dbuf of K-tiles, counted vmcnt(8), 2 barriers/K-tile ----
  stage_kt(0, TP[0], TQ[0], 0);     // 8 loads/wave
  stage_kt(1, TP[0], TQ[0], 64);    // 8 more (16 outstanding)

  for (int i = 0; i < nt; ++i) {
    const bool hn = (i + 1 < nt);
    // t=0
    asm volatile("s_waitcnt vmcnt(8)" ::: "memory");
    __builtin_amdgcn_s_barrier();
    __builtin_amdgcn_sched_barrier(0);
    consume(0);
    __builtin_amdgcn_sched_barrier(0);
    __builtin_amdgcn_s_barrier();
    stage_kt(0, TP[i], TQ[i], 128);
    // t=1
    asm volatile("s_waitcnt vmcnt(8)" ::: "memory");
    __builtin_amdgcn_s_barrier();
    __builtin_amdgcn_sched_barrier(0);
    consume(1);
    __builtin_amdgcn_sched_barrier(0);
    __builtin_amdgcn_s_barrier();
    stage_kt(1, TP[i], TQ[i], 192);
    // t=2
    asm volatile("s_waitcnt vmcnt(8)" ::: "memory");
    __builtin_amdgcn_s_barrier();
    __builtin_amdgcn_sched_barrier(0);
    consume(0);
    __builtin_amdgcn_sched_barrier(0);
    __builtin_amdgcn_s_barrier();
    if (hn) stage_kt(0, TP[i + 1], TQ[i + 1], 0);
    // t=3
    if (hn) { asm volatile("s_waitcnt vmcnt(8)" ::: "memory"); }
    else    { asm volatile("s_waitcnt vmcnt(0)" ::: "memory"); }
    __builtin_amdgcn_s_barrier();
    __builtin_amdgcn_sched_barrier(0);
    consume(1);
    __builtin_amdgcn_sched_barrier(0);
    __builtin_amdgcn_s_barrier();
    if (hn) stage_kt(1, TP[i + 1], TQ[i + 1], 64);
    // epilogue overlaps the next tile's staged loads (pure VALU/LDS)
    epilogue(i, TP[i], TQ[i]);
#pragma unroll
    for (int m = 0; m < 8; ++m)
#pragma unroll
      for (int n = 0; n < 4; ++n) acc[m][n] = z4;
  }

  // ---- flush stashed partials (each thread reads only what it wrote) ----
  {
    const int half = tid >> 8;        // 0/1
    const int rr = tid & 255;
    for (int i = 0; i < nt; ++i) {
      if (half == 0)
        partial[(size_t)TQ[i] * NROWS + TP[i] * 256 + rr] = stashf[i][0][rr];
      else if (TP[i] != TQ[i])
        partial[(size_t)TP[i] * NROWS + TQ[i] * 256 + rr] = stashf[i][1][rr];
    }
  }
}

// ---------------- 3. per-row loss + full reduction (last-block-done finish) ----------------
__global__ __launch_bounds__(256) void d1_kernel(const float* __restrict__ partial,
                                                 const float* __restrict__ pos,
                                                 float* __restrict__ bsum,
                                                 float* __restrict__ out,
                                                 unsigned int* __restrict__ counter) {
  const int row = blockIdx.x * 256 + threadIdx.x;   // 32 blocks x 256
  float s = 0.f;
#pragma unroll 8
  for (int c = 0; c < 32; ++c) s += partial[(size_t)c * NROWS + row];
  const float L = __log2f(s) - pos[row & 4095];     // log2-domain ce
  const float pt = __builtin_amdgcn_exp2f(-L);
  const float ce = 0.69314718056f * L;
  float f = (1.f - pt) * (1.f - pt) * ce;
#pragma unroll
  for (int m = 1; m < 64; m <<= 1) f += __shfl_xor(f, m);
  __shared__ float wsum[4];
  if ((threadIdx.x & 63) == 0) wsum[threadIdx.x >> 6] = f;
  __syncthreads();
  if (threadIdx.x == 0) {
    bsum[blockIdx.x] = wsum[0] + wsum[1] + wsum[2] + wsum[3];
    __threadfence();
    if (atomicAdd(counter, 1u) == 31u) {        // last block: deterministic finish
      __threadfence();
      float v = 0.f;
#pragma unroll
      for (int c = 0; c < 32; ++c) v += ((const volatile float*)bsum)[c];
      out[0] = 0.25f * v / 8192.f;              // ALPHA * mean
    }
  }
}

extern "C" void kernel_launch(void* const* d_in, const int* in_sizes, int n_in,
                              void* d_out, int out_size, void* d_ws, size_t ws_size,
                              hipStream_t stream) {
  const float* zx = (const float*)d_in[0];
  const float* zy = (const float*)d_in[1];
  float* out = (float*)d_out;

  // workspace (~5.02 MiB): zn bf16 | pos | partial[32][8192] | bsum | counter
  unsigned short* zn = (unsigned short*)d_ws;                      // 4 MiB
  float* pos = (float*)((char*)d_ws + (size_t)NROWS * DDIM * 2);   // 16 KiB
  float* partial = pos + 4096;                                     // 32*8192*4 = 1 MiB
  float* bsum = partial + (size_t)32 * NROWS;                      // 128 B
  unsigned int* counter = (unsigned int*)(bsum + 32);              // 4 B

  norm_kernel<<<2048, 256, 0, stream>>>(zx, zy, zn, counter);
  simtri_kernel<<<256, 512, 0, stream>>>(zn, partial, pos);
  d1_kernel<<<32, 256, 0, stream>>>(partial, pos, bsum, out, counter);
}